// Round 1
// baseline (391.621 us; speedup 1.0000x reference)
//
#include <hip/hip_runtime.h>

#define LRELU(v) ((v) > 0.0f ? (v) : 0.2f * (v))

constexpr int F_IN = 128;
constexpr int NH1  = 6;
constexpr int D1   = 192;   // NH1 * 32

// ---------------- GEMM1: h1[N,192] = x[N,128] @ W1[128,192] ----------------
// 256 threads/block, tile 128 rows x 192 cols, K staged in chunks of 32.
// Each thread: 8 rows x 12 cols register tile.
__global__ __launch_bounds__(256) void k_gemm1(const float* __restrict__ x,
                                               const float* __restrict__ W,
                                               float* __restrict__ h1, int N) {
  __shared__ __align__(16) float xs[128][36];   // pad 36: 2-way bank alias only (free)
  __shared__ __align__(16) float ws[32][192];
  const int t = threadIdx.x;
  const int m0 = blockIdx.x * 128;
  const int rloc = t & 15;
  const int c0 = (t >> 4) * 12;
  float acc[8][12];
#pragma unroll
  for (int a = 0; a < 8; ++a)
#pragma unroll
    for (int b = 0; b < 12; ++b) acc[a][b] = 0.0f;

  for (int kc = 0; kc < F_IN; kc += 32) {
    // stage x tile: 128x32 floats = 1024 float4, 4 per thread
#pragma unroll
    for (int i = 0; i < 4; ++i) {
      int f = t + i * 256;
      int row = f >> 3, kv = f & 7;
      int gr = m0 + row;
      float4 v = make_float4(0.f, 0.f, 0.f, 0.f);
      if (gr < N) v = *(const float4*)(x + (size_t)gr * F_IN + kc + kv * 4);
      *(float4*)(&xs[row][kv * 4]) = v;
    }
    // stage W tile: 32x192 floats = 1536 float4, 6 per thread
#pragma unroll
    for (int i = 0; i < 6; ++i) {
      int f = t + i * 256;
      int row = f / 48, cv = f % 48;
      *(float4*)(&ws[row][cv * 4]) = *(const float4*)(W + (size_t)(kc + row) * D1 + cv * 4);
    }
    __syncthreads();
    for (int k4 = 0; k4 < 32; k4 += 4) {
      float4 xv[8];
#pragma unroll
      for (int j = 0; j < 8; ++j) xv[j] = *(const float4*)(&xs[rloc + j * 16][k4]);
#pragma unroll
      for (int kk = 0; kk < 4; ++kk) {
        float wv[12];
        *(float4*)&wv[0] = *(const float4*)(&ws[k4 + kk][c0]);
        *(float4*)&wv[4] = *(const float4*)(&ws[k4 + kk][c0 + 4]);
        *(float4*)&wv[8] = *(const float4*)(&ws[k4 + kk][c0 + 8]);
#pragma unroll
        for (int j = 0; j < 8; ++j) {
          float xk = (kk == 0) ? xv[j].x : (kk == 1) ? xv[j].y : (kk == 2) ? xv[j].z : xv[j].w;
#pragma unroll
          for (int c = 0; c < 12; ++c) acc[j][c] += xk * wv[c];
        }
      }
    }
    __syncthreads();
  }
#pragma unroll
  for (int j = 0; j < 8; ++j) {
    int gr = m0 + rloc + j * 16;
    if (gr < N) {
      float* p = h1 + (size_t)gr * D1 + c0;
      *(float4*)(p)     = make_float4(acc[j][0], acc[j][1], acc[j][2], acc[j][3]);
      *(float4*)(p + 4) = make_float4(acc[j][4], acc[j][5], acc[j][6], acc[j][7]);
      *(float4*)(p + 8) = make_float4(acc[j][8], acc[j][9], acc[j][10], acc[j][11]);
    }
  }
}

// ---------------- attention logits layer 1: al_s/al_d [N,6] ----------------
__global__ void k_al1(const float* __restrict__ h1, const float* __restrict__ a1s,
                      const float* __restrict__ a1d, float* __restrict__ als,
                      float* __restrict__ ald, int N) {
  int idx = blockIdx.x * blockDim.x + threadIdx.x;
  if (idx >= N * NH1) return;
  int n = idx / NH1, h = idx - n * NH1;
  const float4* hp = (const float4*)(h1 + (size_t)n * D1 + h * 32);
  const float4* as = (const float4*)(a1s + h * 32);
  const float4* ad = (const float4*)(a1d + h * 32);
  float ss = 0.f, sd = 0.f;
#pragma unroll
  for (int c = 0; c < 8; ++c) {
    float4 v = hp[c], vs = as[c], vd = ad[c];
    ss += v.x * vs.x + v.y * vs.y + v.z * vs.z + v.w * vs.w;
    sd += v.x * vd.x + v.y * vd.y + v.z * vd.z + v.w * vd.w;
  }
  als[idx] = ss;
  ald[idx] = sd;
}

// ---------------- CSR build: histogram / scan / scatter ----------------
__global__ void k_hist(const int* __restrict__ dst, int* __restrict__ cnt, int E) {
  int e = blockIdx.x * 256 + threadIdx.x;
  if (e < E) atomicAdd(&cnt[dst[e]], 1);
}

__global__ void k_scan1(const int* __restrict__ cnt, int* __restrict__ offs,
                        int* __restrict__ bsum, int N) {
  int t = threadIdx.x;
  int idx = blockIdx.x * 256 + t;
  int lane = t & 63, w = t >> 6;
  int v = (idx < N) ? cnt[idx] : 0;
  int incl = v;
#pragma unroll
  for (int d = 1; d < 64; d <<= 1) {
    int u = __shfl_up(incl, d);
    if (lane >= d) incl += u;
  }
  __shared__ int wt[4];
  if (lane == 63) wt[w] = incl;
  __syncthreads();
  int woff = 0;
  for (int i = 0; i < w; ++i) woff += wt[i];
  if (idx < N) offs[idx] = woff + incl - v;
  if (t == 255) bsum[blockIdx.x] = woff + incl;
}

__global__ void k_scan2(int* __restrict__ bsum, int* __restrict__ boff, int NB) {
  int t = threadIdx.x;
  int lane = t & 63, w = t >> 6;
  int v = (t < NB) ? bsum[t] : 0;
  int incl = v;
#pragma unroll
  for (int d = 1; d < 64; d <<= 1) {
    int u = __shfl_up(incl, d);
    if (lane >= d) incl += u;
  }
  __shared__ int wt[4];
  if (lane == 63) wt[w] = incl;
  __syncthreads();
  int woff = 0;
  for (int i = 0; i < w; ++i) woff += wt[i];
  if (t < NB) boff[t] = woff + incl - v;
}

__global__ void k_scan3(int* __restrict__ offs, int* __restrict__ cursor,
                        const int* __restrict__ boff, const int* __restrict__ bsum,
                        int N, int NB) {
  int idx = blockIdx.x * 256 + threadIdx.x;
  if (idx < N) {
    int v = offs[idx] + boff[blockIdx.x];
    offs[idx] = v;
    cursor[idx] = v;
  }
  if (idx == 0) offs[N] = boff[NB - 1] + bsum[NB - 1];
}

__global__ void k_scatter(const int* __restrict__ src, const int* __restrict__ dst,
                          int* __restrict__ cursor, int* __restrict__ ss, int E) {
  int e = blockIdx.x * 256 + threadIdx.x;
  if (e < E) {
    int d = dst[e];
    int p = atomicAdd(&cursor[d], 1);
    ss[p] = src[e];
  }
}

// ---------------- layer-1 aggregation + fused layer-2 node transform ----------------
// one wave per dst node; self-loop is the implicit (i == cnt) edge.
__global__ __launch_bounds__(256) void k_agg1(
    const float* __restrict__ h1, const float* __restrict__ als, const float* __restrict__ ald,
    const int* __restrict__ offs, const int* __restrict__ srcs,
    const float* __restrict__ b1, const float* __restrict__ W2,
    const float* __restrict__ a2s, const float* __restrict__ a2d,
    float* __restrict__ h2, float* __restrict__ al2s, float* __restrict__ al2d, int N) {
  int wid = threadIdx.x >> 6, lane = threadIdx.x & 63;
  int d = blockIdx.x * 4 + wid;
  if (d >= N) return;
  int off = offs[d], cnt = offs[d + 1] - off;

  float aldh[6];
#pragma unroll
  for (int h = 0; h < 6; ++h) aldh[h] = ald[d * 6 + h];

  // phase A: per-head segment max (incl. self-loop)
  float mh[6];
#pragma unroll
  for (int h = 0; h < 6; ++h) mh[h] = -1e30f;
  for (int i = lane; i <= cnt; i += 64) {
    int s = (i == cnt) ? d : srcs[off + i];
#pragma unroll
    for (int h = 0; h < 6; ++h) {
      float e = als[s * 6 + h] + aldh[h];
      e = LRELU(e);
      mh[h] = fmaxf(mh[h], e);
    }
  }
#pragma unroll
  for (int h = 0; h < 6; ++h)
#pragma unroll
    for (int m = 32; m; m >>= 1) mh[h] = fmaxf(mh[h], __shfl_xor(mh[h], m));

  // phase B: per-head denom
  float dh[6] = {0.f, 0.f, 0.f, 0.f, 0.f, 0.f};
  for (int i = lane; i <= cnt; i += 64) {
    int s = (i == cnt) ? d : srcs[off + i];
#pragma unroll
    for (int h = 0; h < 6; ++h) {
      float e = als[s * 6 + h] + aldh[h];
      e = LRELU(e);
      dh[h] += __expf(e - mh[h]);
    }
  }
#pragma unroll
  for (int h = 0; h < 6; ++h) {
#pragma unroll
    for (int m = 32; m; m >>= 1) dh[h] += __shfl_xor(dh[h], m);
    dh[h] = 1.0f / dh[h];  // inverse denom
  }

  // phase C: message accumulation. lane owns channels lane, lane+64, lane+128
  int b = lane >> 5;
  int cg0 = lane, cg1 = lane + 64, cg2 = lane + 128;
  int hA = b, hB = 2 + b, hC = 4 + b;
  float a0 = 0.f, a1 = 0.f, a2 = 0.f;
  for (int i = 0; i <= cnt; ++i) {
    int s = (i == cnt) ? d : srcs[off + i];
    const float* ap = als + (size_t)s * 6;
    const float* hp = h1 + (size_t)s * D1;
    float e0 = LRELU(ap[hA] + aldh[hA]);
    float e1 = LRELU(ap[hB] + aldh[hB]);
    float e2 = LRELU(ap[hC] + aldh[hC]);
    float w0 = __expf(e0 - mh[hA]) * dh[hA];
    float w1 = __expf(e1 - mh[hB]) * dh[hB];
    float w2 = __expf(e2 - mh[hC]) * dh[hC];
    a0 += w0 * hp[cg0];
    a1 += w1 * hp[cg1];
    a2 += w2 * hp[cg2];
  }

  // epilogue: +b1, ReLU, layer-2 transform h2 = v @ W2, attention logits
  float v0 = fmaxf(a0 + b1[cg0], 0.f);
  float v1 = fmaxf(a1 + b1[cg1], 0.f);
  float v2 = fmaxf(a2 + b1[cg2], 0.f);
  float s0 = v0 * W2[cg0 * 2]     + v1 * W2[cg1 * 2]     + v2 * W2[cg2 * 2];
  float s1 = v0 * W2[cg0 * 2 + 1] + v1 * W2[cg1 * 2 + 1] + v2 * W2[cg2 * 2 + 1];
#pragma unroll
  for (int m = 32; m; m >>= 1) {
    s0 += __shfl_xor(s0, m);
    s1 += __shfl_xor(s1, m);
  }
  if (lane == 0) {
    h2[d * 2] = s0;
    h2[d * 2 + 1] = s1;
    al2s[d] = s0 * a2s[0] + s1 * a2s[1];
    al2d[d] = s0 * a2d[0] + s1 * a2d[1];
  }
}

// ---------------- layer-2 aggregation + bias + log_softmax ----------------
__global__ void k_agg2(const float* __restrict__ h2, const float* __restrict__ al2s,
                       const float* __restrict__ al2d, const int* __restrict__ offs,
                       const int* __restrict__ srcs, const float* __restrict__ b2,
                       float* __restrict__ out, int N) {
  int d = blockIdx.x * 256 + threadIdx.x;
  if (d >= N) return;
  int off = offs[d], cnt = offs[d + 1] - off;
  float ad = al2d[d];
  float m = LRELU(al2s[d] + ad);
  for (int i = 0; i < cnt; ++i) {
    float e = al2s[srcs[off + i]] + ad;
    e = LRELU(e);
    m = fmaxf(m, e);
  }
  float eself = __expf(LRELU(al2s[d] + ad) - m);
  float den = eself;
  float o0 = eself * h2[d * 2], o1 = eself * h2[d * 2 + 1];
  for (int i = 0; i < cnt; ++i) {
    int s = srcs[off + i];
    float e = al2s[s] + ad;
    e = LRELU(e);
    float a = __expf(e - m);
    den += a;
    o0 += a * h2[s * 2];
    o1 += a * h2[s * 2 + 1];
  }
  float inv = 1.0f / den;
  o0 = o0 * inv + b2[0];
  o1 = o1 * inv + b2[1];
  float mm = fmaxf(o0, o1);
  float l = mm + logf(__expf(o0 - mm) + __expf(o1 - mm));
  out[d * 2] = o0 - l;
  out[d * 2 + 1] = o1 - l;
}

extern "C" void kernel_launch(void* const* d_in, const int* in_sizes, int n_in,
                              void* d_out, int out_size, void* d_ws, size_t ws_size,
                              hipStream_t stream) {
  const float* x   = (const float*)d_in[0];
  const int*   ei  = (const int*)d_in[1];
  const float* W1  = (const float*)d_in[2];
  const float* a1s = (const float*)d_in[3];
  const float* a1d = (const float*)d_in[4];
  const float* b1  = (const float*)d_in[5];
  const float* W2  = (const float*)d_in[6];
  const float* a2s = (const float*)d_in[7];
  const float* a2d = (const float*)d_in[8];
  const float* b2  = (const float*)d_in[9];
  float* out = (float*)d_out;

  const int N = in_sizes[0] / F_IN;   // 50000
  const int E = in_sizes[1] / 2;      // 800000
  const int* srcp = ei;
  const int* dstp = ei + E;

  // workspace carve-up (256B aligned)
  char* w = (char*)d_ws;
  auto alloc = [&](size_t bytes) {
    char* p = w;
    w += (bytes + 255) & ~(size_t)255;
    return p;
  };
  float* h1     = (float*)alloc((size_t)N * D1 * 4);
  float* als    = (float*)alloc((size_t)N * NH1 * 4);
  float* ald    = (float*)alloc((size_t)N * NH1 * 4);
  float* h2     = (float*)alloc((size_t)N * 2 * 4);
  float* al2s   = (float*)alloc((size_t)N * 4);
  float* al2d   = (float*)alloc((size_t)N * 4);
  int*   cnt    = (int*)alloc((size_t)N * 4);
  int*   offs   = (int*)alloc((size_t)(N + 1) * 4);
  int*   cursor = (int*)alloc((size_t)N * 4);
  int*   bsum   = (int*)alloc(1024);
  int*   boff   = (int*)alloc(1024);
  int*   ssort  = (int*)alloc((size_t)E * 4);

  const int NB = (N + 255) / 256;     // 196

  hipMemsetAsync(cnt, 0, (size_t)N * 4, stream);

  k_gemm1<<<(N + 127) / 128, 256, 0, stream>>>(x, W1, h1, N);
  k_al1<<<(N * NH1 + 255) / 256, 256, 0, stream>>>(h1, a1s, a1d, als, ald, N);

  k_hist<<<(E + 255) / 256, 256, 0, stream>>>(dstp, cnt, E);
  k_scan1<<<NB, 256, 0, stream>>>(cnt, offs, bsum, N);
  k_scan2<<<1, 256, 0, stream>>>(bsum, boff, NB);
  k_scan3<<<NB, 256, 0, stream>>>(offs, cursor, boff, bsum, N, NB);
  k_scatter<<<(E + 255) / 256, 256, 0, stream>>>(srcp, dstp, cursor, ssort, E);

  k_agg1<<<(N + 3) / 4, 256, 0, stream>>>(h1, als, ald, offs, ssort, b1, W2,
                                          a2s, a2d, h2, al2s, al2d, N);
  k_agg2<<<NB, 256, 0, stream>>>(h2, al2s, al2d, offs, ssort, b2, out, N);
}

// Round 2
// 341.166 us; speedup vs baseline: 1.1479x; 1.1479x over previous
//
#include <hip/hip_runtime.h>

#define LRELU(v) ((v) > 0.0f ? (v) : 0.2f * (v))

constexpr int F_IN = 128;
constexpr int NH1  = 6;
constexpr int D1   = 192;   // NH1 * 32

__device__ __forceinline__ void wave_lds_fence() {
  __builtin_amdgcn_wave_barrier();
  asm volatile("s_waitcnt lgkmcnt(0)" ::: "memory");
  __builtin_amdgcn_wave_barrier();
}

// ---------------- GEMM1: h1[N,192] = x[N,128] @ W1[128,192] ----------------
__global__ __launch_bounds__(256) void k_gemm1(const float* __restrict__ x,
                                               const float* __restrict__ W,
                                               float* __restrict__ h1, int N) {
  __shared__ __align__(16) float xs[128][36];
  __shared__ __align__(16) float ws[32][192];
  const int t = threadIdx.x;
  const int m0 = blockIdx.x * 128;
  const int rloc = t & 15;
  const int c0 = (t >> 4) * 12;
  float acc[8][12];
#pragma unroll
  for (int a = 0; a < 8; ++a)
#pragma unroll
    for (int b = 0; b < 12; ++b) acc[a][b] = 0.0f;

  for (int kc = 0; kc < F_IN; kc += 32) {
#pragma unroll
    for (int i = 0; i < 4; ++i) {
      int f = t + i * 256;
      int row = f >> 3, kv = f & 7;
      int gr = m0 + row;
      float4 v = make_float4(0.f, 0.f, 0.f, 0.f);
      if (gr < N) v = *(const float4*)(x + (size_t)gr * F_IN + kc + kv * 4);
      *(float4*)(&xs[row][kv * 4]) = v;
    }
#pragma unroll
    for (int i = 0; i < 6; ++i) {
      int f = t + i * 256;
      int row = f / 48, cv = f % 48;
      *(float4*)(&ws[row][cv * 4]) = *(const float4*)(W + (size_t)(kc + row) * D1 + cv * 4);
    }
    __syncthreads();
    for (int k4 = 0; k4 < 32; k4 += 4) {
      float4 xv[8];
#pragma unroll
      for (int j = 0; j < 8; ++j) xv[j] = *(const float4*)(&xs[rloc + j * 16][k4]);
#pragma unroll
      for (int kk = 0; kk < 4; ++kk) {
        float wv[12];
        *(float4*)&wv[0] = *(const float4*)(&ws[k4 + kk][c0]);
        *(float4*)&wv[4] = *(const float4*)(&ws[k4 + kk][c0 + 4]);
        *(float4*)&wv[8] = *(const float4*)(&ws[k4 + kk][c0 + 8]);
#pragma unroll
        for (int j = 0; j < 8; ++j) {
          float xk = (kk == 0) ? xv[j].x : (kk == 1) ? xv[j].y : (kk == 2) ? xv[j].z : xv[j].w;
#pragma unroll
          for (int c = 0; c < 12; ++c) acc[j][c] += xk * wv[c];
        }
      }
    }
    __syncthreads();
  }
#pragma unroll
  for (int j = 0; j < 8; ++j) {
    int gr = m0 + rloc + j * 16;
    if (gr < N) {
      float* p = h1 + (size_t)gr * D1 + c0;
      *(float4*)(p)     = make_float4(acc[j][0], acc[j][1], acc[j][2], acc[j][3]);
      *(float4*)(p + 4) = make_float4(acc[j][4], acc[j][5], acc[j][6], acc[j][7]);
      *(float4*)(p + 8) = make_float4(acc[j][8], acc[j][9], acc[j][10], acc[j][11]);
    }
  }
}

// ---------------- attention logits layer 1 ----------------
__global__ void k_al1(const float* __restrict__ h1, const float* __restrict__ a1s,
                      const float* __restrict__ a1d, float* __restrict__ als,
                      float* __restrict__ ald, int N) {
  int idx = blockIdx.x * blockDim.x + threadIdx.x;
  if (idx >= N * NH1) return;
  int n = idx / NH1, h = idx - n * NH1;
  const float4* hp = (const float4*)(h1 + (size_t)n * D1 + h * 32);
  const float4* as = (const float4*)(a1s + h * 32);
  const float4* ad = (const float4*)(a1d + h * 32);
  float ss = 0.f, sd = 0.f;
#pragma unroll
  for (int c = 0; c < 8; ++c) {
    float4 v = hp[c], vs = as[c], vd = ad[c];
    ss += v.x * vs.x + v.y * vs.y + v.z * vs.z + v.w * vs.w;
    sd += v.x * vd.x + v.y * vd.y + v.z * vd.z + v.w * vd.w;
  }
  als[idx] = ss;
  ald[idx] = sd;
}

// ---------------- CSR build ----------------
__global__ void k_hist(const int* __restrict__ dst, int* __restrict__ cnt, int E) {
  int e = blockIdx.x * 256 + threadIdx.x;
  if (e < E) atomicAdd(&cnt[dst[e]], 1);
}

__global__ void k_scan1(const int* __restrict__ cnt, int* __restrict__ offs,
                        int* __restrict__ bsum, int N) {
  int t = threadIdx.x;
  int idx = blockIdx.x * 256 + t;
  int lane = t & 63, w = t >> 6;
  int v = (idx < N) ? cnt[idx] : 0;
  int incl = v;
#pragma unroll
  for (int d = 1; d < 64; d <<= 1) {
    int u = __shfl_up(incl, d);
    if (lane >= d) incl += u;
  }
  __shared__ int wt[4];
  if (lane == 63) wt[w] = incl;
  __syncthreads();
  int woff = 0;
  for (int i = 0; i < w; ++i) woff += wt[i];
  if (idx < N) offs[idx] = woff + incl - v;
  if (t == 255) bsum[blockIdx.x] = woff + incl;
}

__global__ void k_scan2(int* __restrict__ bsum, int* __restrict__ boff, int NB) {
  int t = threadIdx.x;
  int lane = t & 63, w = t >> 6;
  int v = (t < NB) ? bsum[t] : 0;
  int incl = v;
#pragma unroll
  for (int d = 1; d < 64; d <<= 1) {
    int u = __shfl_up(incl, d);
    if (lane >= d) incl += u;
  }
  __shared__ int wt[4];
  if (lane == 63) wt[w] = incl;
  __syncthreads();
  int woff = 0;
  for (int i = 0; i < w; ++i) woff += wt[i];
  if (t < NB) boff[t] = woff + incl - v;
}

__global__ void k_scan3(int* __restrict__ offs, int* __restrict__ cursor,
                        const int* __restrict__ boff, const int* __restrict__ bsum,
                        int N, int NB) {
  int idx = blockIdx.x * 256 + threadIdx.x;
  if (idx < N) {
    int v = offs[idx] + boff[blockIdx.x];
    offs[idx] = v;
    cursor[idx] = v;
  }
  if (idx == 0) offs[N] = boff[NB - 1] + bsum[NB - 1];
}

__global__ void k_scatter(const int* __restrict__ src, const int* __restrict__ dst,
                          int* __restrict__ cursor, int* __restrict__ ss, int E) {
  int e = blockIdx.x * 256 + threadIdx.x;
  if (e < E) {
    int d = dst[e];
    int p = atomicAdd(&cursor[d], 1);
    ss[p] = src[e];
  }
}

// ---------------- layer-1 aggregation + fused layer-2 node transform ----------------
// one wave per dst node; self-loop is implicit edge index cnt.
// no max-subtraction (softmax shift-invariant; logits are O(1) in fp32).
// Alpha computed once per edge, stored normalized in per-wave LDS slab.
__global__ __launch_bounds__(256) void k_agg1(
    const float* __restrict__ h1, const float* __restrict__ als, const float* __restrict__ ald,
    const int* __restrict__ offs, const int* __restrict__ srcs,
    const float* __restrict__ b1, const float* __restrict__ W2,
    const float* __restrict__ a2s, const float* __restrict__ a2d,
    float* __restrict__ h2, float* __restrict__ al2s, float* __restrict__ al2d, int N) {
  // stride 9 words: lane*9 mod 32 hits all banks (gcd(9,32)=1) -> conflict-free writes
  __shared__ float wbuf[4][64][9];
  int wid = threadIdx.x >> 6, lane = threadIdx.x & 63;
  int d = blockIdx.x * 4 + wid;
  if (d >= N) return;
  int off = offs[d], cnt = offs[d + 1] - off;
  int tot = cnt + 1;  // + self loop

  float aldh[6];
  {
    const float* ap = ald + (size_t)d * 6;
    float2 q0 = *(const float2*)ap, q1 = *(const float2*)(ap + 2), q2 = *(const float2*)(ap + 4);
    aldh[0] = q0.x; aldh[1] = q0.y; aldh[2] = q1.x;
    aldh[3] = q1.y; aldh[4] = q2.x; aldh[5] = q2.y;
  }

  float dh[6] = {0.f, 0.f, 0.f, 0.f, 0.f, 0.f};
  int nchunk = (tot + 63) >> 6;

  float a0 = 0.f, a1 = 0.f, a2 = 0.f;
  const int b = lane >> 5;
  const int cg0 = lane, cg1 = lane + 64, cg2 = lane + 128;

  auto body = [&](int j) {
    float w0 = wbuf[wid][j][b];
    float w1 = wbuf[wid][j][2 + b];
    float w2 = wbuf[wid][j][4 + b];
    int s = __float_as_int(wbuf[wid][j][6]);
    const float* hp = h1 + (size_t)s * D1;
    a0 = fmaf(w0, hp[cg0], a0);
    a1 = fmaf(w1, hp[cg1], a1);
    a2 = fmaf(w2, hp[cg2], a2);
  };
  auto jloop = [&](int jmax) {
    int j = 0;
    for (; j + 3 < jmax; j += 4) { body(j); body(j + 1); body(j + 2); body(j + 3); }
    for (; j < jmax; ++j) body(j);
  };

  if (nchunk == 1) {
    // fast path: whole segment in one chunk; exps computed exactly once.
    float wreg[6];
    int sreg = 0;
    if (lane < tot) {
      int s = (lane == cnt) ? d : srcs[off + lane];
      sreg = s;
      const float* ap = als + (size_t)s * 6;
      float2 p0 = *(const float2*)ap, p1 = *(const float2*)(ap + 2), p2 = *(const float2*)(ap + 4);
      float ev[6] = {p0.x, p0.y, p1.x, p1.y, p2.x, p2.y};
#pragma unroll
      for (int h = 0; h < 6; ++h) {
        float e = ev[h] + aldh[h];
        e = LRELU(e);
        wreg[h] = __expf(e);
        dh[h] = wreg[h];
      }
    }
#pragma unroll
    for (int h = 0; h < 6; ++h) {
#pragma unroll
      for (int m = 32; m; m >>= 1) dh[h] += __shfl_xor(dh[h], m);
      dh[h] = 1.0f / dh[h];
    }
    if (lane < tot) {
#pragma unroll
      for (int h = 0; h < 6; ++h) wbuf[wid][lane][h] = wreg[h] * dh[h];
      wbuf[wid][lane][6] = __int_as_float(sreg);
    }
    wave_lds_fence();
    jloop(tot);
  } else {
    // general path (degree >= 64: essentially never for Poisson(16), but correct)
    for (int c = 0; c < nchunk; ++c) {
      int i = c * 64 + lane;
      if (i < tot) {
        int s = (i == cnt) ? d : srcs[off + i];
        const float* ap = als + (size_t)s * 6;
        float2 p0 = *(const float2*)ap, p1 = *(const float2*)(ap + 2), p2 = *(const float2*)(ap + 4);
        float ev[6] = {p0.x, p0.y, p1.x, p1.y, p2.x, p2.y};
#pragma unroll
        for (int h = 0; h < 6; ++h) {
          float e = ev[h] + aldh[h];
          e = LRELU(e);
          dh[h] += __expf(e);
        }
      }
    }
#pragma unroll
    for (int h = 0; h < 6; ++h) {
#pragma unroll
      for (int m = 32; m; m >>= 1) dh[h] += __shfl_xor(dh[h], m);
      dh[h] = 1.0f / dh[h];
    }
    for (int c = 0; c < nchunk; ++c) {
      int i = c * 64 + lane;
      if (i < tot) {
        int s = (i == cnt) ? d : srcs[off + i];
        const float* ap = als + (size_t)s * 6;
        float2 p0 = *(const float2*)ap, p1 = *(const float2*)(ap + 2), p2 = *(const float2*)(ap + 4);
        float ev[6] = {p0.x, p0.y, p1.x, p1.y, p2.x, p2.y};
#pragma unroll
        for (int h = 0; h < 6; ++h) {
          float e = ev[h] + aldh[h];
          e = LRELU(e);
          wbuf[wid][lane][h] = __expf(e) * dh[h];
        }
        wbuf[wid][lane][6] = __int_as_float(s);
      }
      wave_lds_fence();
      int jmax = tot - c * 64;
      if (jmax > 64) jmax = 64;
      jloop(jmax);
      wave_lds_fence();
    }
  }

  // epilogue: +b1, ReLU, layer-2 transform, attention logits
  float v0 = fmaxf(a0 + b1[cg0], 0.f);
  float v1 = fmaxf(a1 + b1[cg1], 0.f);
  float v2 = fmaxf(a2 + b1[cg2], 0.f);
  float s0 = v0 * W2[cg0 * 2]     + v1 * W2[cg1 * 2]     + v2 * W2[cg2 * 2];
  float s1 = v0 * W2[cg0 * 2 + 1] + v1 * W2[cg1 * 2 + 1] + v2 * W2[cg2 * 2 + 1];
#pragma unroll
  for (int m = 32; m; m >>= 1) {
    s0 += __shfl_xor(s0, m);
    s1 += __shfl_xor(s1, m);
  }
  if (lane == 0) {
    h2[d * 2] = s0;
    h2[d * 2 + 1] = s1;
    al2s[d] = s0 * a2s[0] + s1 * a2s[1];
    al2d[d] = s0 * a2d[0] + s1 * a2d[1];
  }
}

// ---------------- layer-2 aggregation + bias + log_softmax ----------------
// 8 lanes per node, single pass (no max subtraction), shfl-reduce within group.
__global__ __launch_bounds__(256) void k_agg2(
    const float* __restrict__ h2, const float* __restrict__ al2s,
    const float* __restrict__ al2d, const int* __restrict__ offs,
    const int* __restrict__ srcs, const float* __restrict__ b2,
    float* __restrict__ out, int N) {
  int tid = blockIdx.x * 256 + threadIdx.x;
  int g = tid >> 3, r = tid & 7;
  if (g >= N) return;
  int off = offs[g], cnt = offs[g + 1] - off;
  int tot = cnt + 1;
  float ad = al2d[g];
  float den = 0.f, o0 = 0.f, o1 = 0.f;
  for (int i = r; i < tot; i += 8) {
    int s = (i == cnt) ? g : srcs[off + i];
    float e = al2s[s] + ad;
    e = LRELU(e);
    float a = __expf(e);
    float2 hv = *(const float2*)(h2 + (size_t)s * 2);
    den += a;
    o0 = fmaf(a, hv.x, o0);
    o1 = fmaf(a, hv.y, o1);
  }
#pragma unroll
  for (int m = 4; m; m >>= 1) {
    den += __shfl_xor(den, m);
    o0 += __shfl_xor(o0, m);
    o1 += __shfl_xor(o1, m);
  }
  if (r == 0) {
    float inv = 1.0f / den;
    o0 = o0 * inv + b2[0];
    o1 = o1 * inv + b2[1];
    float mm = fmaxf(o0, o1);
    float l = mm + logf(__expf(o0 - mm) + __expf(o1 - mm));
    *(float2*)(out + (size_t)g * 2) = make_float2(o0 - l, o1 - l);
  }
}

extern "C" void kernel_launch(void* const* d_in, const int* in_sizes, int n_in,
                              void* d_out, int out_size, void* d_ws, size_t ws_size,
                              hipStream_t stream) {
  const float* x   = (const float*)d_in[0];
  const int*   ei  = (const int*)d_in[1];
  const float* W1  = (const float*)d_in[2];
  const float* a1s = (const float*)d_in[3];
  const float* a1d = (const float*)d_in[4];
  const float* b1  = (const float*)d_in[5];
  const float* W2  = (const float*)d_in[6];
  const float* a2s = (const float*)d_in[7];
  const float* a2d = (const float*)d_in[8];
  const float* b2  = (const float*)d_in[9];
  float* out = (float*)d_out;

  const int N = in_sizes[0] / F_IN;   // 50000
  const int E = in_sizes[1] / 2;      // 800000
  const int* srcp = ei;
  const int* dstp = ei + E;

  char* w = (char*)d_ws;
  auto alloc = [&](size_t bytes) {
    char* p = w;
    w += (bytes + 255) & ~(size_t)255;
    return p;
  };
  float* h1     = (float*)alloc((size_t)N * D1 * 4);
  float* als    = (float*)alloc((size_t)N * NH1 * 4);
  float* ald    = (float*)alloc((size_t)N * NH1 * 4);
  float* h2     = (float*)alloc((size_t)N * 2 * 4);
  float* al2s   = (float*)alloc((size_t)N * 4);
  float* al2d   = (float*)alloc((size_t)N * 4);
  int*   cnt    = (int*)alloc((size_t)N * 4);
  int*   offs   = (int*)alloc((size_t)(N + 1) * 4);
  int*   cursor = (int*)alloc((size_t)N * 4);
  int*   bsum   = (int*)alloc(1024);
  int*   boff   = (int*)alloc(1024);
  int*   ssort  = (int*)alloc((size_t)E * 4);

  const int NB = (N + 255) / 256;

  hipMemsetAsync(cnt, 0, (size_t)N * 4, stream);

  k_gemm1<<<(N + 127) / 128, 256, 0, stream>>>(x, W1, h1, N);
  k_al1<<<(N * NH1 + 255) / 256, 256, 0, stream>>>(h1, a1s, a1d, als, ald, N);

  k_hist<<<(E + 255) / 256, 256, 0, stream>>>(dstp, cnt, E);
  k_scan1<<<NB, 256, 0, stream>>>(cnt, offs, bsum, N);
  k_scan2<<<1, 256, 0, stream>>>(bsum, boff, NB);
  k_scan3<<<NB, 256, 0, stream>>>(offs, cursor, boff, bsum, N, NB);
  k_scatter<<<(E + 255) / 256, 256, 0, stream>>>(srcp, dstp, cursor, ssort, E);

  k_agg1<<<(N + 3) / 4, 256, 0, stream>>>(h1, als, ald, offs, ssort, b1, W2,
                                          a2s, a2d, h2, al2s, al2d, N);
  k_agg2<<<(N * 8 + 255) / 256, 256, 0, stream>>>(h2, al2s, al2d, offs, ssort, b2, out, N);
}

// Round 3
// 291.934 us; speedup vs baseline: 1.3415x; 1.1686x over previous
//
#include <hip/hip_runtime.h>
#include <hip/hip_fp16.h>

#define LRELU(v) ((v) > 0.0f ? (v) : 0.2f * (v))

constexpr int F_IN = 128;
constexpr int NH1  = 6;
constexpr int D1   = 192;   // NH1 * 32

__device__ __forceinline__ void wave_lds_fence() {
  __builtin_amdgcn_wave_barrier();
  asm volatile("s_waitcnt lgkmcnt(0)" ::: "memory");
  __builtin_amdgcn_wave_barrier();
}

// ---------------- GEMM1: h1h[N,192] (fp16) = x[N,128] @ W1[128,192] ----------------
__global__ __launch_bounds__(256) void k_gemm1(const float* __restrict__ x,
                                               const float* __restrict__ W,
                                               __half* __restrict__ h1h, int N) {
  __shared__ __align__(16) float xs[128][36];
  __shared__ __align__(16) float ws[32][192];
  const int t = threadIdx.x;
  const int m0 = blockIdx.x * 128;
  const int rloc = t & 15;
  const int c0 = (t >> 4) * 12;
  float acc[8][12];
#pragma unroll
  for (int a = 0; a < 8; ++a)
#pragma unroll
    for (int b = 0; b < 12; ++b) acc[a][b] = 0.0f;

  for (int kc = 0; kc < F_IN; kc += 32) {
#pragma unroll
    for (int i = 0; i < 4; ++i) {
      int f = t + i * 256;
      int row = f >> 3, kv = f & 7;
      int gr = m0 + row;
      float4 v = make_float4(0.f, 0.f, 0.f, 0.f);
      if (gr < N) v = *(const float4*)(x + (size_t)gr * F_IN + kc + kv * 4);
      *(float4*)(&xs[row][kv * 4]) = v;
    }
#pragma unroll
    for (int i = 0; i < 6; ++i) {
      int f = t + i * 256;
      int row = f / 48, cv = f % 48;
      *(float4*)(&ws[row][cv * 4]) = *(const float4*)(W + (size_t)(kc + row) * D1 + cv * 4);
    }
    __syncthreads();
    for (int k4 = 0; k4 < 32; k4 += 4) {
      float4 xv[8];
#pragma unroll
      for (int j = 0; j < 8; ++j) xv[j] = *(const float4*)(&xs[rloc + j * 16][k4]);
#pragma unroll
      for (int kk = 0; kk < 4; ++kk) {
        float wv[12];
        *(float4*)&wv[0] = *(const float4*)(&ws[k4 + kk][c0]);
        *(float4*)&wv[4] = *(const float4*)(&ws[k4 + kk][c0 + 4]);
        *(float4*)&wv[8] = *(const float4*)(&ws[k4 + kk][c0 + 8]);
#pragma unroll
        for (int j = 0; j < 8; ++j) {
          float xk = (kk == 0) ? xv[j].x : (kk == 1) ? xv[j].y : (kk == 2) ? xv[j].z : xv[j].w;
#pragma unroll
          for (int c = 0; c < 12; ++c) acc[j][c] += xk * wv[c];
        }
      }
    }
    __syncthreads();
  }
#pragma unroll
  for (int j = 0; j < 8; ++j) {
    int gr = m0 + rloc + j * 16;
    if (gr < N) {
      ushort hs[12];
#pragma unroll
      for (int c = 0; c < 12; ++c) hs[c] = __half_as_ushort(__float2half(acc[j][c]));
      ushort* p = (ushort*)(h1h + (size_t)gr * D1 + c0);  // byte off 24*(t>>4): 8B aligned
      *(ushort4*)(p)     = *(ushort4*)(&hs[0]);
      *(ushort4*)(p + 4) = *(ushort4*)(&hs[4]);
      *(ushort4*)(p + 8) = *(ushort4*)(&hs[8]);
    }
  }
}

// ---------------- attention logits layer 1 (fp16 h1 input) ----------------
__global__ void k_al1(const __half* __restrict__ h1h, const float* __restrict__ a1s,
                      const float* __restrict__ a1d, float* __restrict__ als,
                      float* __restrict__ ald, int N) {
  int idx = blockIdx.x * blockDim.x + threadIdx.x;
  if (idx >= N * NH1) return;
  int n = idx / NH1, h = idx - n * NH1;
  const __half2* hp = (const __half2*)(h1h + (size_t)n * D1 + h * 32);
  const float2* as = (const float2*)(a1s + h * 32);
  const float2* ad = (const float2*)(a1d + h * 32);
  float ss = 0.f, sd = 0.f;
#pragma unroll
  for (int c = 0; c < 16; ++c) {
    float2 v = __half22float2(hp[c]);
    float2 vs = as[c], vd = ad[c];
    ss += v.x * vs.x + v.y * vs.y;
    sd += v.x * vd.x + v.y * vd.y;
  }
  als[idx] = ss;
  ald[idx] = sd;
}

// ---------------- CSR build ----------------
__global__ void k_hist(const int* __restrict__ dst, int* __restrict__ cnt, int E) {
  int e = blockIdx.x * 256 + threadIdx.x;
  if (e < E) atomicAdd(&cnt[dst[e]], 1);
}

__global__ void k_scan1(const int* __restrict__ cnt, int* __restrict__ offs,
                        int* __restrict__ bsum, int N) {
  int t = threadIdx.x;
  int idx = blockIdx.x * 256 + t;
  int lane = t & 63, w = t >> 6;
  int v = (idx < N) ? cnt[idx] : 0;
  int incl = v;
#pragma unroll
  for (int d = 1; d < 64; d <<= 1) {
    int u = __shfl_up(incl, d);
    if (lane >= d) incl += u;
  }
  __shared__ int wt[4];
  if (lane == 63) wt[w] = incl;
  __syncthreads();
  int woff = 0;
  for (int i = 0; i < w; ++i) woff += wt[i];
  if (idx < N) offs[idx] = woff + incl - v;
  if (t == 255) bsum[blockIdx.x] = woff + incl;
}

__global__ void k_scan2(int* __restrict__ bsum, int* __restrict__ boff, int NB) {
  int t = threadIdx.x;
  int lane = t & 63, w = t >> 6;
  int v = (t < NB) ? bsum[t] : 0;
  int incl = v;
#pragma unroll
  for (int d = 1; d < 64; d <<= 1) {
    int u = __shfl_up(incl, d);
    if (lane >= d) incl += u;
  }
  __shared__ int wt[4];
  if (lane == 63) wt[w] = incl;
  __syncthreads();
  int woff = 0;
  for (int i = 0; i < w; ++i) woff += wt[i];
  if (t < NB) boff[t] = woff + incl - v;
}

__global__ void k_scan3(int* __restrict__ offs, int* __restrict__ cursor,
                        const int* __restrict__ boff, const int* __restrict__ bsum,
                        int N, int NB) {
  int idx = blockIdx.x * 256 + threadIdx.x;
  if (idx < N) {
    int v = offs[idx] + boff[blockIdx.x];
    offs[idx] = v;
    cursor[idx] = v;
  }
  if (idx == 0) offs[N] = boff[NB - 1] + bsum[NB - 1];
}

__global__ void k_scatter(const int* __restrict__ src, const int* __restrict__ dst,
                          int* __restrict__ cursor, int* __restrict__ ss, int E) {
  int e = blockIdx.x * 256 + threadIdx.x;
  if (e < E) {
    int d = dst[e];
    int p = atomicAdd(&cursor[d], 1);
    ss[p] = src[e];
  }
}

// ---------------- layer-1 aggregation + fused layer-2 node transform ----------------
// one wave per dst node; self-loop implicit at index cnt; no max subtraction.
// lane owns channels {2*lane, 2*lane+1} (head lane>>4) and {128+lane} (head 4+(lane>>5)).
// per-edge LDS slab row: [w0..w5, src] stride 9 (conflict-free writes, broadcast reads).
__global__ __launch_bounds__(256) void k_agg1(
    const __half* __restrict__ h1h, const float* __restrict__ als, const float* __restrict__ ald,
    const int* __restrict__ offs, const int* __restrict__ srcs,
    const float* __restrict__ b1, const float* __restrict__ W2,
    const float* __restrict__ a2s, const float* __restrict__ a2d,
    float* __restrict__ h2, float* __restrict__ al2s, float* __restrict__ al2d, int N) {
  __shared__ float wbuf[4][64][9];
  int wid = threadIdx.x >> 6, lane = threadIdx.x & 63;
  int d = blockIdx.x * 4 + wid;
  if (d >= N) return;
  int off = offs[d], cnt = offs[d + 1] - off;
  int tot = cnt + 1;

  float aldh[6];
  {
    const float* ap = ald + (size_t)d * 6;
    float2 q0 = *(const float2*)ap, q1 = *(const float2*)(ap + 2), q2 = *(const float2*)(ap + 4);
    aldh[0] = q0.x; aldh[1] = q0.y; aldh[2] = q1.x;
    aldh[3] = q1.y; aldh[4] = q2.x; aldh[5] = q2.y;
  }

  float dh[6] = {0.f, 0.f, 0.f, 0.f, 0.f, 0.f};
  int nchunk = (tot + 63) >> 6;

  float a0 = 0.f, a1 = 0.f, a2 = 0.f;
  const int hw = lane >> 4;        // head for word channels
  const int hh = 4 + (lane >> 5);  // head for half channel

  auto body = [&](int j) {
    float w_a = wbuf[wid][j][hw];
    float w_b = wbuf[wid][j][hh];
    int s = __float_as_int(wbuf[wid][j][6]);
    const __half* hp = h1h + (size_t)s * D1;
    float2 v = __half22float2(*(const __half2*)(hp + 2 * lane));
    float vh = __half2float(hp[128 + lane]);
    a0 = fmaf(w_a, v.x, a0);
    a1 = fmaf(w_a, v.y, a1);
    a2 = fmaf(w_b, vh, a2);
  };
  auto jloop = [&](int jmax) {
    int j = 0;
    for (; j + 3 < jmax; j += 4) { body(j); body(j + 1); body(j + 2); body(j + 3); }
    for (; j < jmax; ++j) body(j);
  };

  if (nchunk == 1) {
    float wreg[6];
    int sreg = 0;
    if (lane < tot) {
      int s = (lane == cnt) ? d : srcs[off + lane];
      sreg = s;
      const float* ap = als + (size_t)s * 6;
      float2 p0 = *(const float2*)ap, p1 = *(const float2*)(ap + 2), p2 = *(const float2*)(ap + 4);
      float ev[6] = {p0.x, p0.y, p1.x, p1.y, p2.x, p2.y};
#pragma unroll
      for (int h = 0; h < 6; ++h) {
        float e = ev[h] + aldh[h];
        e = LRELU(e);
        wreg[h] = __expf(e);
        dh[h] = wreg[h];
      }
    }
#pragma unroll
    for (int h = 0; h < 6; ++h) {
#pragma unroll
      for (int m = 32; m; m >>= 1) dh[h] += __shfl_xor(dh[h], m);
      dh[h] = 1.0f / dh[h];
    }
    if (lane < tot) {
#pragma unroll
      for (int h = 0; h < 6; ++h) wbuf[wid][lane][h] = wreg[h] * dh[h];
      wbuf[wid][lane][6] = __int_as_float(sreg);
    }
    wave_lds_fence();
    jloop(tot);
  } else {
    for (int c = 0; c < nchunk; ++c) {
      int i = c * 64 + lane;
      if (i < tot) {
        int s = (i == cnt) ? d : srcs[off + i];
        const float* ap = als + (size_t)s * 6;
        float2 p0 = *(const float2*)ap, p1 = *(const float2*)(ap + 2), p2 = *(const float2*)(ap + 4);
        float ev[6] = {p0.x, p0.y, p1.x, p1.y, p2.x, p2.y};
#pragma unroll
        for (int h = 0; h < 6; ++h) {
          float e = ev[h] + aldh[h];
          e = LRELU(e);
          dh[h] += __expf(e);
        }
      }
    }
#pragma unroll
    for (int h = 0; h < 6; ++h) {
#pragma unroll
      for (int m = 32; m; m >>= 1) dh[h] += __shfl_xor(dh[h], m);
      dh[h] = 1.0f / dh[h];
    }
    for (int c = 0; c < nchunk; ++c) {
      int i = c * 64 + lane;
      if (i < tot) {
        int s = (i == cnt) ? d : srcs[off + i];
        const float* ap = als + (size_t)s * 6;
        float2 p0 = *(const float2*)ap, p1 = *(const float2*)(ap + 2), p2 = *(const float2*)(ap + 4);
        float ev[6] = {p0.x, p0.y, p1.x, p1.y, p2.x, p2.y};
#pragma unroll
        for (int h = 0; h < 6; ++h) {
          float e = ev[h] + aldh[h];
          e = LRELU(e);
          wbuf[wid][lane][h] = __expf(e) * dh[h];
        }
        wbuf[wid][lane][6] = __int_as_float(s);
      }
      wave_lds_fence();
      int jmax = tot - c * 64;
      if (jmax > 64) jmax = 64;
      jloop(jmax);
      wave_lds_fence();
    }
  }

  // epilogue: +b1, ReLU, layer-2 transform, attention logits
  float2 bv = *(const float2*)(b1 + 2 * lane);
  float v0 = fmaxf(a0 + bv.x, 0.f);
  float v1 = fmaxf(a1 + bv.y, 0.f);
  float v2 = fmaxf(a2 + b1[128 + lane], 0.f);
  float4 ww = *(const float4*)(W2 + 4 * lane);          // rows 2l, 2l+1
  float2 wh = *(const float2*)(W2 + (128 + lane) * 2);  // row 128+l
  float s0 = v0 * ww.x + v1 * ww.z + v2 * wh.x;
  float s1 = v0 * ww.y + v1 * ww.w + v2 * wh.y;
#pragma unroll
  for (int m = 32; m; m >>= 1) {
    s0 += __shfl_xor(s0, m);
    s1 += __shfl_xor(s1, m);
  }
  if (lane == 0) {
    h2[d * 2] = s0;
    h2[d * 2 + 1] = s1;
    al2s[d] = s0 * a2s[0] + s1 * a2s[1];
    al2d[d] = s0 * a2d[0] + s1 * a2d[1];
  }
}

// ---------------- layer-2 aggregation + bias + log_softmax ----------------
__global__ __launch_bounds__(256) void k_agg2(
    const float* __restrict__ h2, const float* __restrict__ al2s,
    const float* __restrict__ al2d, const int* __restrict__ offs,
    const int* __restrict__ srcs, const float* __restrict__ b2,
    float* __restrict__ out, int N) {
  int tid = blockIdx.x * 256 + threadIdx.x;
  int g = tid >> 3, r = tid & 7;
  if (g >= N) return;
  int off = offs[g], cnt = offs[g + 1] - off;
  int tot = cnt + 1;
  float ad = al2d[g];
  float den = 0.f, o0 = 0.f, o1 = 0.f;
  for (int i = r; i < tot; i += 8) {
    int s = (i == cnt) ? g : srcs[off + i];
    float e = al2s[s] + ad;
    e = LRELU(e);
    float a = __expf(e);
    float2 hv = *(const float2*)(h2 + (size_t)s * 2);
    den += a;
    o0 = fmaf(a, hv.x, o0);
    o1 = fmaf(a, hv.y, o1);
  }
#pragma unroll
  for (int m = 4; m; m >>= 1) {
    den += __shfl_xor(den, m);
    o0 += __shfl_xor(o0, m);
    o1 += __shfl_xor(o1, m);
  }
  if (r == 0) {
    float inv = 1.0f / den;
    o0 = o0 * inv + b2[0];
    o1 = o1 * inv + b2[1];
    float mm = fmaxf(o0, o1);
    float l = mm + logf(__expf(o0 - mm) + __expf(o1 - mm));
    *(float2*)(out + (size_t)g * 2) = make_float2(o0 - l, o1 - l);
  }
}

extern "C" void kernel_launch(void* const* d_in, const int* in_sizes, int n_in,
                              void* d_out, int out_size, void* d_ws, size_t ws_size,
                              hipStream_t stream) {
  const float* x   = (const float*)d_in[0];
  const int*   ei  = (const int*)d_in[1];
  const float* W1  = (const float*)d_in[2];
  const float* a1s = (const float*)d_in[3];
  const float* a1d = (const float*)d_in[4];
  const float* b1  = (const float*)d_in[5];
  const float* W2  = (const float*)d_in[6];
  const float* a2s = (const float*)d_in[7];
  const float* a2d = (const float*)d_in[8];
  const float* b2  = (const float*)d_in[9];
  float* out = (float*)d_out;

  const int N = in_sizes[0] / F_IN;   // 50000
  const int E = in_sizes[1] / 2;      // 800000
  const int* srcp = ei;
  const int* dstp = ei + E;

  char* w = (char*)d_ws;
  auto alloc = [&](size_t bytes) {
    char* p = w;
    w += (bytes + 255) & ~(size_t)255;
    return p;
  };
  __half* h1h   = (__half*)alloc((size_t)N * D1 * 2);
  float* als    = (float*)alloc((size_t)N * NH1 * 4);
  float* ald    = (float*)alloc((size_t)N * NH1 * 4);
  float* h2     = (float*)alloc((size_t)N * 2 * 4);
  float* al2s   = (float*)alloc((size_t)N * 4);
  float* al2d   = (float*)alloc((size_t)N * 4);
  int*   cnt    = (int*)alloc((size_t)N * 4);
  int*   offs   = (int*)alloc((size_t)(N + 1) * 4);
  int*   cursor = (int*)alloc((size_t)N * 4);
  int*   bsum   = (int*)alloc(1024);
  int*   boff   = (int*)alloc(1024);
  int*   ssort  = (int*)alloc((size_t)E * 4);

  const int NB = (N + 255) / 256;

  hipMemsetAsync(cnt, 0, (size_t)N * 4, stream);

  k_gemm1<<<(N + 127) / 128, 256, 0, stream>>>(x, W1, h1h, N);
  k_al1<<<(N * NH1 + 255) / 256, 256, 0, stream>>>(h1h, a1s, a1d, als, ald, N);

  k_hist<<<(E + 255) / 256, 256, 0, stream>>>(dstp, cnt, E);
  k_scan1<<<NB, 256, 0, stream>>>(cnt, offs, bsum, N);
  k_scan2<<<1, 256, 0, stream>>>(bsum, boff, NB);
  k_scan3<<<NB, 256, 0, stream>>>(offs, cursor, boff, bsum, N, NB);
  k_scatter<<<(E + 255) / 256, 256, 0, stream>>>(srcp, dstp, cursor, ssort, E);

  k_agg1<<<(N + 3) / 4, 256, 0, stream>>>(h1h, als, ald, offs, ssort, b1, W2,
                                          a2s, a2d, h2, al2s, al2d, N);
  k_agg2<<<(N * 8 + 255) / 256, 256, 0, stream>>>(h2, al2s, al2d, offs, ssort, b2, out, N);
}